// Round 1
// baseline (1506.958 us; speedup 1.0000x reference)
//
#include <hip/hip_runtime.h>
#include <math.h>

#define NPTS 50000
#define NSP  4000
#define KNN  11

// Brute-force exact kNN (k=11) + Voronoi-edge distance epilogue.
// One thread per point. spoints are read via wave-uniform float4 loads
// (scalarizable to s_load), top-11 kept as sorted register arrays with
// jax.lax.top_k tie semantics (ties -> lower index wins).
__global__ __launch_bounds__(256) void voronoi_knn_kernel(
    const float* __restrict__ pts,   // (2, NPTS, 3)
    const float* __restrict__ spts,  // (2, NSP, 3)
    float* __restrict__ out)         // (2, NPTS)
{
    const int tid = blockIdx.x * blockDim.x + threadIdx.x;
    const int b   = blockIdx.y;
    if (tid >= NPTS) return;

    const float* sp = spts + (size_t)b * NSP * 3;
    const float* pp = pts + ((size_t)b * NPTS + tid) * 3;
    const float px = pp[0], py = pp[1], pz = pp[2];

    float d2s[KNN];
    int   idxs[KNN];
#pragma unroll
    for (int k = 0; k < KNN; ++k) { d2s[k] = 3.4e38f; idxs[k] = 0; }

    for (int j = 0; j < NSP; j += 4) {
        // 12 floats = 4 spoints; j*12 bytes is 16B-aligned (j % 4 == 0).
        const float4 q0 = *(const float4*)(sp + j * 3);
        const float4 q1 = *(const float4*)(sp + j * 3 + 4);
        const float4 q2 = *(const float4*)(sp + j * 3 + 8);
        const float sx[4] = {q0.x, q0.w, q1.z, q2.y};
        const float sy[4] = {q0.y, q1.x, q1.w, q2.z};
        const float sz[4] = {q0.z, q1.y, q2.x, q2.w};
#pragma unroll
        for (int u = 0; u < 4; ++u) {
            const float dx = px - sx[u];
            const float dy = py - sy[u];
            const float dz = pz - sz[u];
            const float nd = dx * dx + dy * dy + dz * dz;
            if (nd < d2s[KNN - 1]) {   // strict <: tie keeps existing (lower idx)
                float pd = nd;
                int   pi = j + u;
#pragma unroll
                for (int k = 0; k < KNN; ++k) {
                    const float cd = d2s[k];
                    const int   ci = idxs[k];
                    const bool  c  = (cd > nd);   // strict >: stable insert
                    if (c) { d2s[k] = pd; idxs[k] = pi; pd = cd; pi = ci; }
                }
            }
        }
    }

    // Epilogue: inside = nearest; edges = next 10.
    const float* c0 = sp + idxs[0] * 3;
    const float ix = c0[0], iy = c0[1], iz = c0[2];
    const float vx = px - ix, vy = py - iy, vz = pz - iz;
    float best = 3.4e38f;
#pragma unroll
    for (int k = 1; k < KNN; ++k) {
        const float* ck = sp + idxs[k] * 3;
        const float ex = ck[0] - ix;
        const float ey = ck[1] - iy;
        const float ez = ck[2] - iz;
        const float ee = ex * ex + ey * ey + ez * ez;
        const float el = sqrtf(ee);
        const float vl = (vx * ex + vy * ey + vz * ez) / el;
        const float t  = vl - 0.5f * el;
        best = fminf(best, t * t);
    }
    out[(size_t)b * NPTS + tid] = best;
}

extern "C" void kernel_launch(void* const* d_in, const int* in_sizes, int n_in,
                              void* d_out, int out_size, void* d_ws, size_t ws_size,
                              hipStream_t stream) {
    const float* pts  = (const float*)d_in[0];   // (2, 50000, 3)
    const float* spts = (const float*)d_in[1];   // (2, 4000, 3)
    float* out = (float*)d_out;                  // (2, 50000)

    dim3 grid((NPTS + 255) / 256, 2);
    dim3 block(256);
    voronoi_knn_kernel<<<grid, block, 0, stream>>>(pts, spts, out);
}

// Round 2
// 540.934 us; speedup vs baseline: 2.7858x; 2.7858x over previous
//
#include <hip/hip_runtime.h>
#include <math.h>

#define NPTS 50000
#define NSP  4000
#define BIG  3.4e38f

#define MED3(a,b,c) __builtin_amdgcn_fmed3f((a),(b),(c))

// Two-pass exact kNN(11) + Voronoi edge distance.
// Pass A: values-only top-11 via med3 sorted-insert chain (1 op/level) + argmin index.
// Pass B: rescan; every candidate with nd <= d10 (except the nearest) contributes
//         one edge term directly to the running min (order-independent).
// spoints staged in LDS (48 KB), read wave-uniform (broadcast, conflict-free).
__global__ __launch_bounds__(256, 1) void voronoi_kernel(
    const float* __restrict__ pts,   // (2, NPTS, 3)
    const float* __restrict__ spts,  // (2, NSP, 3)
    float* __restrict__ out)         // (2, NPTS)
{
    __shared__ float lsp[NSP * 3];

    const int b = blockIdx.y;
    const float* sp = spts + (size_t)b * NSP * 3;
    for (int i = threadIdx.x; i < NSP * 3 / 4; i += 256)
        ((float4*)lsp)[i] = ((const float4*)sp)[i];
    __syncthreads();

    const int tid = blockIdx.x * 256 + threadIdx.x;
    if (tid >= NPTS) return;

    const float* pp = pts + ((size_t)b * NPTS + tid) * 3;
    const float px = pp[0], py = pp[1], pz = pp[2];

    // Sorted top-11 squared distances, d0 smallest. Explicit scalars -> VGPRs.
    float d0 = BIG, d1 = BIG, d2 = BIG, d3 = BIG, d4 = BIG, d5 = BIG;
    float d6 = BIG, d7 = BIG, d8 = BIG, d9 = BIG, d10 = BIG;
    int i0 = 0;  // argmin (nearest spoint index); strict < keeps lowest index on ties

#define STEP_A(sx, sy, sz, jj) {                                   \
        const float dx = px - (sx);                                \
        const float dy = py - (sy);                                \
        const float dz = pz - (sz);                                \
        const float nd = fmaf(dx, dx, fmaf(dy, dy, dz * dz));      \
        if (nd < d10) {                                            \
            if (nd < d0) i0 = (jj);                                \
            d10 = MED3(d9, d10, nd);                               \
            d9  = MED3(d8, d9,  nd);                               \
            d8  = MED3(d7, d8,  nd);                               \
            d7  = MED3(d6, d7,  nd);                               \
            d6  = MED3(d5, d6,  nd);                               \
            d5  = MED3(d4, d5,  nd);                               \
            d4  = MED3(d3, d4,  nd);                               \
            d3  = MED3(d2, d3,  nd);                               \
            d2  = MED3(d1, d2,  nd);                               \
            d1  = MED3(d0, d1,  nd);                               \
            d0  = fminf(d0, nd);                                   \
        } }

    for (int j = 0; j < NSP; j += 4) {
        const float4 q0 = *(const float4*)(lsp + j * 3);
        const float4 q1 = *(const float4*)(lsp + j * 3 + 4);
        const float4 q2 = *(const float4*)(lsp + j * 3 + 8);
        STEP_A(q0.x, q0.y, q0.z, j);
        STEP_A(q0.w, q1.x, q1.y, j + 1);
        STEP_A(q1.z, q1.w, q2.x, j + 2);
        STEP_A(q2.y, q2.z, q2.w, j + 3);
    }

    // Inside = nearest spoint; v = point - inside.
    const float ix = lsp[i0 * 3], iy = lsp[i0 * 3 + 1], iz = lsp[i0 * 3 + 2];
    const float vx = px - ix, vy = py - iy, vz = pz - iz;
    float best = BIG;

    // t = dot/|e| - |e|/2  ->  t^2 = (dot - ee/2)^2 / ee   (no sqrt needed)
#define STEP_B(sx, sy, sz, jj) {                                   \
        const float dx = px - (sx);                                \
        const float dy = py - (sy);                                \
        const float dz = pz - (sz);                                \
        const float nd = fmaf(dx, dx, fmaf(dy, dy, dz * dz));      \
        if (nd <= d10 && (jj) != i0) {                             \
            const float ex = (sx) - ix;                            \
            const float ey = (sy) - iy;                            \
            const float ez = (sz) - iz;                            \
            const float ee = fmaf(ex, ex, fmaf(ey, ey, ez * ez));  \
            const float dt = fmaf(vx, ex, fmaf(vy, ey, vz * ez));  \
            const float u  = fmaf(-0.5f, ee, dt);                  \
            const float t2 = u * u * __builtin_amdgcn_rcpf(ee);    \
            best = fminf(best, t2);                                \
        } }

    for (int j = 0; j < NSP; j += 4) {
        const float4 q0 = *(const float4*)(lsp + j * 3);
        const float4 q1 = *(const float4*)(lsp + j * 3 + 4);
        const float4 q2 = *(const float4*)(lsp + j * 3 + 8);
        STEP_B(q0.x, q0.y, q0.z, j);
        STEP_B(q0.w, q1.x, q1.y, j + 1);
        STEP_B(q1.z, q1.w, q2.x, j + 2);
        STEP_B(q2.y, q2.z, q2.w, j + 3);
    }

    out[(size_t)b * NPTS + tid] = best;
}

extern "C" void kernel_launch(void* const* d_in, const int* in_sizes, int n_in,
                              void* d_out, int out_size, void* d_ws, size_t ws_size,
                              hipStream_t stream) {
    const float* pts  = (const float*)d_in[0];   // (2, 50000, 3)
    const float* spts = (const float*)d_in[1];   // (2, 4000, 3)
    float* out = (float*)d_out;                  // (2, 50000)

    dim3 grid((NPTS + 255) / 256, 2);
    dim3 block(256);
    voronoi_kernel<<<grid, block, 0, stream>>>(pts, spts, out);
}

// Round 3
// 510.758 us; speedup vs baseline: 2.9504x; 1.0591x over previous
//
#include <hip/hip_runtime.h>
#include <math.h>

#define NPTS 50000
#define NSP  4000
#define HALF 2000
#define BIG  3.4e38f

#define MED3(a,b,c) __builtin_amdgcn_fmed3f((a),(b),(c))

// Exact kNN(11) + Voronoi edge distance, candidate-split 2-way.
// Lane pair (2i,2i+1) owns one point: even lane scans spoints [0,2000),
// odd lane [2000,4000). Each lane keeps a values-only sorted top-11 via a
// med3 chain + local argmin. Lists merged in-register via shfl_xor(1) using
// the two-sorted-lists order-statistic formula; pass B rescans each half with
// the global 11th distance and accumulates the edge min directly.
__global__ __launch_bounds__(256, 3) void voronoi_kernel(
    const float* __restrict__ pts,   // (2, NPTS, 3)
    const float* __restrict__ spts,  // (2, NSP, 3)
    float* __restrict__ out)         // (2, NPTS)
{
    __shared__ float lsp[NSP * 3];

    const int b = blockIdx.y;
    const float* sp = spts + (size_t)b * NSP * 3;
    for (int i = threadIdx.x; i < NSP * 3 / 4; i += 256)
        ((float4*)lsp)[i] = ((const float4*)sp)[i];
    __syncthreads();

    const int p    = blockIdx.x * 128 + (threadIdx.x >> 1);
    const int half = threadIdx.x & 1;
    if (p >= NPTS) return;   // pair-uniform: both lanes of a pair drop together

    const float* pp = pts + ((size_t)b * NPTS + p) * 3;
    const float px = pp[0], py = pp[1], pz = pp[2];

    const float* msp  = lsp + half * (HALF * 3);  // my half's LDS base
    const int    jbase = half * HALF;

    // Local sorted top-11 (d0 smallest) + local argmin index.
    float d0 = BIG, d1 = BIG, d2 = BIG, d3 = BIG, d4 = BIG, d5 = BIG;
    float d6 = BIG, d7 = BIG, d8 = BIG, d9 = BIG, d10 = BIG;
    int i0 = 0;

#define STEP_A(sx, sy, sz, jj) {                                   \
        const float dx = px - (sx);                                \
        const float dy = py - (sy);                                \
        const float dz = pz - (sz);                                \
        const float nd = fmaf(dx, dx, fmaf(dy, dy, dz * dz));      \
        if (nd < d10) {                                            \
            if (nd < d0) i0 = (jj);                                \
            d10 = MED3(d9, d10, nd);                               \
            d9  = MED3(d8, d9,  nd);                               \
            d8  = MED3(d7, d8,  nd);                               \
            d7  = MED3(d6, d7,  nd);                               \
            d6  = MED3(d5, d6,  nd);                               \
            d5  = MED3(d4, d5,  nd);                               \
            d4  = MED3(d3, d4,  nd);                               \
            d3  = MED3(d2, d3,  nd);                               \
            d2  = MED3(d1, d2,  nd);                               \
            d1  = MED3(d0, d1,  nd);                               \
            d0  = fminf(d0, nd);                                   \
        } }

    for (int j = 0; j < HALF; j += 4) {
        const float4 q0 = *(const float4*)(msp + j * 3);
        const float4 q1 = *(const float4*)(msp + j * 3 + 4);
        const float4 q2 = *(const float4*)(msp + j * 3 + 8);
        STEP_A(q0.x, q0.y, q0.z, jbase + j);
        STEP_A(q0.w, q1.x, q1.y, jbase + j + 1);
        STEP_A(q1.z, q1.w, q2.x, jbase + j + 2);
        STEP_A(q2.y, q2.z, q2.w, jbase + j + 3);
    }

    // ---- Merge with partner lane (lane^1) ----
    float pl[11];
    pl[0]  = __shfl_xor(d0, 1);  pl[1] = __shfl_xor(d1, 1);
    pl[2]  = __shfl_xor(d2, 1);  pl[3] = __shfl_xor(d3, 1);
    pl[4]  = __shfl_xor(d4, 1);  pl[5] = __shfl_xor(d5, 1);
    pl[6]  = __shfl_xor(d6, 1);  pl[7] = __shfl_xor(d7, 1);
    pl[8]  = __shfl_xor(d8, 1);  pl[9] = __shfl_xor(d9, 1);
    pl[10] = __shfl_xor(d10, 1);

    // 11th-smallest of the union: min over splits of max(L[i-1], P[10-i]).
    float g = fminf(d10, pl[10]);            // i=11 and i=0
    g = fminf(g, fmaxf(d0, pl[9]));
    g = fminf(g, fmaxf(d1, pl[8]));
    g = fminf(g, fmaxf(d2, pl[7]));
    g = fminf(g, fmaxf(d3, pl[6]));
    g = fminf(g, fmaxf(d4, pl[5]));
    g = fminf(g, fmaxf(d5, pl[4]));
    g = fminf(g, fmaxf(d6, pl[3]));
    g = fminf(g, fmaxf(d7, pl[2]));
    g = fminf(g, fmaxf(d8, pl[1]));
    g = fminf(g, fmaxf(d9, pl[0]));
    const float d10g = g;

    // Global argmin; ties -> lower spoint index (= even lane's half).
    const int   pi0 = __shfl_xor(i0, 1);
    const float pd0 = pl[0];
    const bool takeP = (pd0 < d0) || (pd0 == d0 && half == 1);
    const int i0g = takeP ? pi0 : i0;

    const float ix = lsp[i0g * 3], iy = lsp[i0g * 3 + 1], iz = lsp[i0g * 3 + 2];
    const float vx = px - ix, vy = py - iy, vz = pz - iz;
    float best = BIG;

    // t^2 = (dot - ee/2)^2 / ee  (sqrt-free)
#define STEP_B(sx, sy, sz, jj) {                                   \
        const float dx = px - (sx);                                \
        const float dy = py - (sy);                                \
        const float dz = pz - (sz);                                \
        const float nd = fmaf(dx, dx, fmaf(dy, dy, dz * dz));      \
        if (nd <= d10g && (jj) != i0g) {                           \
            const float ex = (sx) - ix;                            \
            const float ey = (sy) - iy;                            \
            const float ez = (sz) - iz;                            \
            const float ee = fmaf(ex, ex, fmaf(ey, ey, ez * ez));  \
            const float dt = fmaf(vx, ex, fmaf(vy, ey, vz * ez));  \
            const float u  = fmaf(-0.5f, ee, dt);                  \
            const float t2 = u * u * __builtin_amdgcn_rcpf(ee);    \
            best = fminf(best, t2);                                \
        } }

    for (int j = 0; j < HALF; j += 4) {
        const float4 q0 = *(const float4*)(msp + j * 3);
        const float4 q1 = *(const float4*)(msp + j * 3 + 4);
        const float4 q2 = *(const float4*)(msp + j * 3 + 8);
        STEP_B(q0.x, q0.y, q0.z, jbase + j);
        STEP_B(q0.w, q1.x, q1.y, jbase + j + 1);
        STEP_B(q1.z, q1.w, q2.x, jbase + j + 2);
        STEP_B(q2.y, q2.z, q2.w, jbase + j + 3);
    }

    best = fminf(best, __shfl_xor(best, 1));
    if (half == 0) out[(size_t)b * NPTS + p] = best;
}

extern "C" void kernel_launch(void* const* d_in, const int* in_sizes, int n_in,
                              void* d_out, int out_size, void* d_ws, size_t ws_size,
                              hipStream_t stream) {
    const float* pts  = (const float*)d_in[0];   // (2, 50000, 3)
    const float* spts = (const float*)d_in[1];   // (2, 4000, 3)
    float* out = (float*)d_out;                  // (2, 50000)

    dim3 grid((NPTS + 127) / 128, 2);   // 391 x 2 blocks, 128 points/block
    dim3 block(256);
    voronoi_kernel<<<grid, block, 0, stream>>>(pts, spts, out);
}

// Round 4
// 419.597 us; speedup vs baseline: 3.5914x; 1.2173x over previous
//
#include <hip/hip_runtime.h>
#include <math.h>

#define NPTS 50000
#define NSP  4000
#define QS   1000      // spoints per lane-quarter
#define BIG  3.4e38f

#define MED3(a,b,c) __builtin_amdgcn_fmed3f((a),(b),(c))

// Exact kNN(11) + Voronoi edge distance, candidate-split 4-way.
// Lane quad (4q..4q+3) owns one point; lane q scans spoints [q*1000,(q+1)*1000).
// Pass A: branchless values-only top-11 med3 chain (no-op when nd>=d10) + argmin.
// Merge: shfl_xor(1) full insert-merge, then shfl_xor(2) order-statistic for d10g.
// Pass B: rescan with wave-uniform __ballot guard; edge min accumulated directly.
// Block 512 = 8 waves, LDS 48KB -> 3 blocks/CU -> 6 waves/SIMD.
__global__ __launch_bounds__(512, 6) void voronoi_kernel(
    const float* __restrict__ pts,   // (2, NPTS, 3)
    const float* __restrict__ spts,  // (2, NSP, 3)
    float* __restrict__ out)         // (2, NPTS)
{
    __shared__ float lsp[NSP * 3];

    const int b = blockIdx.y;
    const float* sp = spts + (size_t)b * NSP * 3;
    for (int i = threadIdx.x; i < NSP * 3 / 4; i += 512)
        ((float4*)lsp)[i] = ((const float4*)sp)[i];
    __syncthreads();

    const int p = blockIdx.x * 128 + (threadIdx.x >> 2);
    const int q = threadIdx.x & 3;
    if (p >= NPTS) return;   // quad-uniform exit

    const float* pp = pts + ((size_t)b * NPTS + p) * 3;
    const float px = pp[0], py = pp[1], pz = pp[2];

    const float* msp = lsp + q * (QS * 3);  // my quarter's LDS base
    const int jb = q * QS;

    // Local sorted top-11 (d0 smallest) + local argmin index. All in VGPRs.
    float d0 = BIG, d1 = BIG, d2 = BIG, d3 = BIG, d4 = BIG, d5 = BIG;
    float d6 = BIG, d7 = BIG, d8 = BIG, d9 = BIG, d10 = BIG;
    int i0 = jb;

    // Branchless: med3 chain is a no-op when nd >= d10. Distance form kept
    // bit-identical to round 2/3 (matches ref's top-11 set on this data).
#define STEP_A(sx, sy, sz, jj) {                                   \
        const float dx = px - (sx);                                \
        const float dy = py - (sy);                                \
        const float dz = pz - (sz);                                \
        const float nd = fmaf(dx, dx, fmaf(dy, dy, dz * dz));      \
        d10 = MED3(d9, d10, nd);                                   \
        d9  = MED3(d8, d9,  nd);                                   \
        d8  = MED3(d7, d8,  nd);                                   \
        d7  = MED3(d6, d7,  nd);                                   \
        d6  = MED3(d5, d6,  nd);                                   \
        d5  = MED3(d4, d5,  nd);                                   \
        d4  = MED3(d3, d4,  nd);                                   \
        d3  = MED3(d2, d3,  nd);                                   \
        d2  = MED3(d1, d2,  nd);                                   \
        d1  = MED3(d0, d1,  nd);                                   \
        i0  = (nd < d0) ? (jj) : i0;                               \
        d0  = fminf(d0, nd);                                       \
    }

    for (int j = 0; j < QS; j += 4) {
        const float4 q0 = *(const float4*)(msp + j * 3);
        const float4 q1 = *(const float4*)(msp + j * 3 + 4);
        const float4 q2 = *(const float4*)(msp + j * 3 + 8);
        STEP_A(q0.x, q0.y, q0.z, jb + j);
        STEP_A(q0.w, q1.x, q1.y, jb + j + 1);
        STEP_A(q1.z, q1.w, q2.x, jb + j + 2);
        STEP_A(q2.y, q2.z, q2.w, jb + j + 3);
    }

    // ---- Argmin reduce over the quad (lexicographic: lower index on ties) ----
    {
        float s0 = d0; int ii = i0;
#pragma unroll
        for (int m = 1; m <= 2; m <<= 1) {
            const float ps = __shfl_xor(s0, m);
            const int   pi = __shfl_xor(ii, m);
            const bool take = (ps < s0) || (ps == s0 && pi < ii);
            s0 = take ? ps : s0;
            ii = take ? pi : ii;
        }
        i0 = ii;
    }

#define INS(v) {                                                   \
        d10 = MED3(d9, d10, (v));                                  \
        d9  = MED3(d8, d9,  (v));                                  \
        d8  = MED3(d7, d8,  (v));                                  \
        d7  = MED3(d6, d7,  (v));                                  \
        d6  = MED3(d5, d6,  (v));                                  \
        d5  = MED3(d4, d5,  (v));                                  \
        d4  = MED3(d3, d4,  (v));                                  \
        d3  = MED3(d2, d3,  (v));                                  \
        d2  = MED3(d1, d2,  (v));                                  \
        d1  = MED3(d0, d1,  (v));                                  \
        d0  = fminf(d0, (v));                                      \
    }

    // Level 1: full insert-merge with lane^1 (need the merged sorted list).
    {
        const float p0 = __shfl_xor(d0, 1),  p1 = __shfl_xor(d1, 1);
        const float p2 = __shfl_xor(d2, 1),  p3 = __shfl_xor(d3, 1);
        const float p4 = __shfl_xor(d4, 1),  p5 = __shfl_xor(d5, 1);
        const float p6 = __shfl_xor(d6, 1),  p7 = __shfl_xor(d7, 1);
        const float p8 = __shfl_xor(d8, 1),  p9 = __shfl_xor(d9, 1);
        const float pA = __shfl_xor(d10, 1);
        INS(p0); INS(p1); INS(p2); INS(p3); INS(p4); INS(p5);
        INS(p6); INS(p7); INS(p8); INS(p9); INS(pA);
    }

    // Level 2: only the union 11th is needed -> order-statistic formula.
    float d10g;
    {
        const float p0 = __shfl_xor(d0, 2),  p1 = __shfl_xor(d1, 2);
        const float p2 = __shfl_xor(d2, 2),  p3 = __shfl_xor(d3, 2);
        const float p4 = __shfl_xor(d4, 2),  p5 = __shfl_xor(d5, 2);
        const float p6 = __shfl_xor(d6, 2),  p7 = __shfl_xor(d7, 2);
        const float p8 = __shfl_xor(d8, 2),  p9 = __shfl_xor(d9, 2);
        const float pA = __shfl_xor(d10, 2);
        float g = fminf(d10, pA);
        g = fminf(g, fmaxf(d0, p9));
        g = fminf(g, fmaxf(d1, p8));
        g = fminf(g, fmaxf(d2, p7));
        g = fminf(g, fmaxf(d3, p6));
        g = fminf(g, fmaxf(d4, p5));
        g = fminf(g, fmaxf(d5, p4));
        g = fminf(g, fmaxf(d6, p3));
        g = fminf(g, fmaxf(d7, p2));
        g = fminf(g, fmaxf(d8, p1));
        g = fminf(g, fmaxf(d9, p0));
        d10g = g;
    }

    const int i0g = i0;
    const float ix = lsp[i0g * 3], iy = lsp[i0g * 3 + 1], iz = lsp[i0g * 3 + 2];
    const float vx = px - ix, vy = py - iy, vz = pz - iz;
    float best = BIG;

    // Pass B: wave-uniform ballot guard (any-lane admit ~16%/step at 4-way split).
    // t^2 = (dot - ee/2)^2 / ee  (sqrt-free)
#define STEP_B(sx, sy, sz, jj) {                                   \
        const float dx = px - (sx);                                \
        const float dy = py - (sy);                                \
        const float dz = pz - (sz);                                \
        const float nd = fmaf(dx, dx, fmaf(dy, dy, dz * dz));      \
        const bool adm = (nd <= d10g) && ((jj) != i0g);            \
        if (__ballot(adm)) {                                       \
            const float ex = (sx) - ix;                            \
            const float ey = (sy) - iy;                            \
            const float ez = (sz) - iz;                            \
            const float ee = fmaf(ex, ex, fmaf(ey, ey, ez * ez));  \
            const float dt = fmaf(vx, ex, fmaf(vy, ey, vz * ez));  \
            const float u  = fmaf(-0.5f, ee, dt);                  \
            const float t2 = u * u * __builtin_amdgcn_rcpf(ee);    \
            best = adm ? fminf(best, t2) : best;                   \
        } }

    for (int j = 0; j < QS; j += 4) {
        const float4 q0 = *(const float4*)(msp + j * 3);
        const float4 q1 = *(const float4*)(msp + j * 3 + 4);
        const float4 q2 = *(const float4*)(msp + j * 3 + 8);
        STEP_B(q0.x, q0.y, q0.z, jb + j);
        STEP_B(q0.w, q1.x, q1.y, jb + j + 1);
        STEP_B(q1.z, q1.w, q2.x, jb + j + 2);
        STEP_B(q2.y, q2.z, q2.w, jb + j + 3);
    }

    // Final min over the quad; lane q==0 writes.
    best = fminf(best, __shfl_xor(best, 1));
    best = fminf(best, __shfl_xor(best, 2));
    if (q == 0) out[(size_t)b * NPTS + p] = best;
}

extern "C" void kernel_launch(void* const* d_in, const int* in_sizes, int n_in,
                              void* d_out, int out_size, void* d_ws, size_t ws_size,
                              hipStream_t stream) {
    const float* pts  = (const float*)d_in[0];   // (2, 50000, 3)
    const float* spts = (const float*)d_in[1];   // (2, 4000, 3)
    float* out = (float*)d_out;                  // (2, 50000)

    dim3 grid((NPTS + 127) / 128, 2);   // 391 x 2 blocks, 128 points/block
    dim3 block(512);
    voronoi_kernel<<<grid, block, 0, stream>>>(pts, spts, out);
}

// Round 5
// 389.151 us; speedup vs baseline: 3.8724x; 1.0782x over previous
//
#include <hip/hip_runtime.h>
#include <math.h>

#define NPTS 50000
#define NSP  4000
#define NQ   8           // candidate split: one wave per eighth
#define QS   (NSP / NQ)  // 500 candidates per wave
#define BIG  3.4e38f

#define MED3(a,b,c) __builtin_amdgcn_fmed3f((a),(b),(c))

// Exact kNN(11) + Voronoi edge distance.
// Wave = 64 points x one eighth of spoints (wave-uniform candidate stream ->
// scalar s_load, ZERO LDS in the hot loops; each lane owns one point).
// Pass A: branchless values-only top-11 med3 chain + lexicographic argmin.
// Merge: 8 per-eighth lists per point exchanged via LDS, union top-11 by
// med3-insertion (exact), argmin lexicographic (lower index wins ties).
// Pass B: rescan own eighth with union d10; edge min accumulated directly.
// Block 512 = 8 waves = the 8 eighths of a 64-point group.
__global__ __launch_bounds__(512, 8) void voronoi_kernel(
    const float* __restrict__ pts,   // (2, NPTS, 3)
    const float* __restrict__ spts,  // (2, NSP, 3)
    float* __restrict__ out)         // (2, NPTS)
{
    __shared__ float lds_d[NQ][64][13];  // sorted top-11 (pad 13: stride coprime 32)
    __shared__ int   lds_i[NQ][64];      // local argmin index
    __shared__ float lds_b[NQ][64];      // per-eighth edge-min

    const int b    = blockIdx.y;
    const int lane = threadIdx.x & 63;
    const int qw   = threadIdx.x >> 6;   // wave id = eighth id (wave-uniform)

    int p = blockIdx.x * 64 + lane;
    const bool valid = (p < NPTS);
    if (!valid) p = NPTS - 1;            // clamp; lanes stay active for merge

    const float* pp = pts + ((size_t)b * NPTS + p) * 3;
    const float px = pp[0], py = pp[1], pz = pp[2];

    const float* sp = spts + (size_t)b * NSP * 3 + qw * (QS * 3);  // uniform base
    const int jb = qw * QS;

    // Sorted top-11 (d0 smallest) + local argmin. All lane-private VGPRs.
    float d0 = BIG, d1 = BIG, d2 = BIG, d3 = BIG, d4 = BIG, d5 = BIG;
    float d6 = BIG, d7 = BIG, d8 = BIG, d9 = BIG, d10 = BIG;
    int i0 = jb;

    // Distance form kept bit-identical to rounds 2-4.
#define STEP_A(sx, sy, sz, jj) {                                   \
        const float dx = px - (sx);                                \
        const float dy = py - (sy);                                \
        const float dz = pz - (sz);                                \
        const float nd = fmaf(dx, dx, fmaf(dy, dy, dz * dz));      \
        d10 = MED3(d9, d10, nd);                                   \
        d9  = MED3(d8, d9,  nd);                                   \
        d8  = MED3(d7, d8,  nd);                                   \
        d7  = MED3(d6, d7,  nd);                                   \
        d6  = MED3(d5, d6,  nd);                                   \
        d5  = MED3(d4, d5,  nd);                                   \
        d4  = MED3(d3, d4,  nd);                                   \
        d3  = MED3(d2, d3,  nd);                                   \
        d2  = MED3(d1, d2,  nd);                                   \
        d1  = MED3(d0, d1,  nd);                                   \
        i0  = (nd < d0) ? (jj) : i0;                               \
        d0  = fminf(d0, nd);                                       \
    }

    for (int j = 0; j < QS; j += 4) {
        // Wave-uniform addresses -> scalar loads (SMEM pipe), no LDS/VMEM.
        const float4 q0 = *(const float4*)(sp + j * 3);
        const float4 q1 = *(const float4*)(sp + j * 3 + 4);
        const float4 q2 = *(const float4*)(sp + j * 3 + 8);
        STEP_A(q0.x, q0.y, q0.z, jb + j);
        STEP_A(q0.w, q1.x, q1.y, jb + j + 1);
        STEP_A(q1.z, q1.w, q2.x, jb + j + 2);
        STEP_A(q2.y, q2.z, q2.w, jb + j + 3);
    }

    // ---- Publish local lists ----
    lds_d[qw][lane][0]  = d0;  lds_d[qw][lane][1]  = d1;
    lds_d[qw][lane][2]  = d2;  lds_d[qw][lane][3]  = d3;
    lds_d[qw][lane][4]  = d4;  lds_d[qw][lane][5]  = d5;
    lds_d[qw][lane][6]  = d6;  lds_d[qw][lane][7]  = d7;
    lds_d[qw][lane][8]  = d8;  lds_d[qw][lane][9]  = d9;
    lds_d[qw][lane][10] = d10;
    lds_i[qw][lane] = i0;
    __syncthreads();

    // ---- Global argmin (lexicographic: lower original index wins ties) ----
    float gb = BIG; int gi = 0x7fffffff;
#pragma unroll
    for (int q = 0; q < NQ; ++q) {
        const float dq = lds_d[q][lane][0];
        const int   iq = lds_i[q][lane];
        const bool take = (dq < gb) || (dq == gb && iq < gi);
        gb = take ? dq : gb;
        gi = take ? iq : gi;
    }

    // ---- Union top-11: insert the 7 foreign lists into own chain (exact) ----
#define INS(v) {                                                   \
        d10 = MED3(d9, d10, (v));                                  \
        d9  = MED3(d8, d9,  (v));                                  \
        d8  = MED3(d7, d8,  (v));                                  \
        d7  = MED3(d6, d7,  (v));                                  \
        d6  = MED3(d5, d6,  (v));                                  \
        d5  = MED3(d4, d5,  (v));                                  \
        d4  = MED3(d3, d4,  (v));                                  \
        d3  = MED3(d2, d3,  (v));                                  \
        d2  = MED3(d1, d2,  (v));                                  \
        d1  = MED3(d0, d1,  (v));                                  \
        d0  = fminf(d0, (v));                                      \
    }
#pragma unroll
    for (int q = 0; q < NQ; ++q) {
        if (q == qw) continue;           // wave-uniform test
#pragma unroll
        for (int k = 0; k < 11; ++k) INS(lds_d[q][lane][k]);
    }
    const float d10g = d10;              // union 11th-smallest
    const int   i0g  = gi;

    // Inside point coords (lane-varying gather, once).
    const float* cp = spts + (size_t)b * NSP * 3 + (size_t)i0g * 3;
    const float ix = cp[0], iy = cp[1], iz = cp[2];
    const float vx = px - ix, vy = py - iy, vz = pz - iz;
    float best = BIG;

    // Pass B over own eighth. t^2 = (dot - ee/2)^2 / ee  (sqrt-free).
#define STEP_B(sx, sy, sz, jj) {                                   \
        const float dx = px - (sx);                                \
        const float dy = py - (sy);                                \
        const float dz = pz - (sz);                                \
        const float nd = fmaf(dx, dx, fmaf(dy, dy, dz * dz));      \
        const bool adm = (nd <= d10g) && ((jj) != i0g);            \
        if (__ballot(adm)) {                                       \
            const float ex = (sx) - ix;                            \
            const float ey = (sy) - iy;                            \
            const float ez = (sz) - iz;                            \
            const float ee = fmaf(ex, ex, fmaf(ey, ey, ez * ez));  \
            const float dt = fmaf(vx, ex, fmaf(vy, ey, vz * ez));  \
            const float u  = fmaf(-0.5f, ee, dt);                  \
            const float t2 = u * u * __builtin_amdgcn_rcpf(ee);    \
            best = adm ? fminf(best, t2) : best;                   \
        } }

    for (int j = 0; j < QS; j += 4) {
        const float4 q0 = *(const float4*)(sp + j * 3);
        const float4 q1 = *(const float4*)(sp + j * 3 + 4);
        const float4 q2 = *(const float4*)(sp + j * 3 + 8);
        STEP_B(q0.x, q0.y, q0.z, jb + j);
        STEP_B(q0.w, q1.x, q1.y, jb + j + 1);
        STEP_B(q1.z, q1.w, q2.x, jb + j + 2);
        STEP_B(q2.y, q2.z, q2.w, jb + j + 3);
    }

    // ---- Final min across the 8 eighths ----
    lds_b[qw][lane] = best;
    __syncthreads();
    if (qw == 0) {
        float m = lds_b[0][lane];
#pragma unroll
        for (int q = 1; q < NQ; ++q) m = fminf(m, lds_b[q][lane]);
        if (valid) out[(size_t)b * NPTS + p] = m;
    }
}

extern "C" void kernel_launch(void* const* d_in, const int* in_sizes, int n_in,
                              void* d_out, int out_size, void* d_ws, size_t ws_size,
                              hipStream_t stream) {
    const float* pts  = (const float*)d_in[0];   // (2, 50000, 3)
    const float* spts = (const float*)d_in[1];   // (2, 4000, 3)
    float* out = (float*)d_out;                  // (2, 50000)

    dim3 grid((NPTS + 63) / 64, 2);   // 782 x 2 blocks, 64 points/block
    dim3 block(512);                  // 8 waves = 8 candidate-eighths
    voronoi_kernel<<<grid, block, 0, stream>>>(pts, spts, out);
}